// Round 1
// baseline (302.095 us; speedup 1.0000x reference)
//
#include <hip/hip_runtime.h>
#include <math.h>

// Shapes: B=32, S=512, I=64, H=512, E=8, P=96, O=64, EM=512; D = S*I = 32768.
#define DIMK 32768

__device__ __forceinline__ void fma4(float4& a, float s, const float4 w) {
  a.x += s * w.x; a.y += s * w.y; a.z += s * w.z; a.w += s * w.w;
}

__device__ __forceinline__ float fsel(const float4& v, int kk) {
  return kk == 0 ? v.x : kk == 1 ? v.y : kk == 2 ? v.z : v.w;
}

__device__ __forceinline__ float block_sum(float v, float* red, int n) {
  int t = threadIdx.x;
  red[t] = v;
  __syncthreads();
  for (int s = n >> 1; s > 0; s >>= 1) {
    if (t < s) red[t] += red[t + s];
    __syncthreads();
  }
  float r = red[0];
  __syncthreads();
  return r;
}

// ---------------------------------------------------------------------------
// gemm1: part[ks][b][m] = x(32 x 32768)[,k-slice ks] @ gW1[k-slice][m-tile].
// grid (2 mt of 256 m, 128 ks of 256 k) = 256 blocks (1/CU), block 256.
// Tile 32b x 256m x 256k. Thread = 8b x 4m (mf = t&63 -> m, bg = t>>6 -> b-octet).
// LDS-pipe-pressure-optimized: W read = one dense 1KB ds_read_b128 per k per
// wave; A read = wave-uniform float4 (broadcast) covering 4 k per b-row.
// W sub-staged 32k at a time, register-prefetched so global loads overlap the
// 2048-cycle compute of the previous sub-stage. LDS 64 KB.
__global__ __launch_bounds__(256) void gemm1(const float* __restrict__ x,
                                             const float* __restrict__ gW1,
                                             float* __restrict__ part) {
  const int mt = blockIdx.x, ks = blockIdx.y;
  const int m0 = mt * 256, k0 = ks * 256;
  const int t = threadIdx.x;
  __shared__ float As[32 * 256];   // 32 b x 256 k (k contiguous; reads are uniform/broadcast)
  __shared__ float Ws[32 * 256];   // sub-stage: 32 k x 256 m (reads are dense 1KB/wave)

  // stage A: 2048 float4, 8 per thread, coalesced (1KB per wave-instr per b-row)
#pragma unroll
  for (int j = 0; j < 8; ++j) {
    int i = t + j * 256, b = i >> 6, q = i & 63;
    *(float4*)&As[b * 256 + q * 4] = *(const float4*)(x + (size_t)b * DIMK + k0 + q * 4);
  }
  // prefetch W sub-stage 0 into registers (8 float4/thread)
  const float* Wp = gW1 + (size_t)k0 * 512 + m0;
  float4 wreg[8];
#pragma unroll
  for (int j = 0; j < 8; ++j) {
    int i = t + j * 256, r = i >> 6, q = i & 63;
    wreg[j] = *(const float4*)(Wp + (size_t)r * 512 + q * 4);
  }

  const int mf4 = (t & 63) * 4;    // m-offset within tile
  const int bg = t >> 6;           // b-octet: b = bg*8 .. bg*8+7
  float4 acc[8];
#pragma unroll
  for (int j = 0; j < 8; ++j) acc[j] = make_float4(0.f, 0.f, 0.f, 0.f);
  const float* a0 = &As[bg * 8 * 256];

  for (int s = 0; s < 8; ++s) {
    __syncthreads();  // previous-stage readers done (s=0: also covers A stores)
#pragma unroll
    for (int j = 0; j < 8; ++j) {
      int i = t + j * 256, r = i >> 6, q = i & 63;
      *(float4*)&Ws[r * 256 + q * 4] = wreg[j];
    }
    __syncthreads();
    if (s < 7) {
      const float* Wn = Wp + (size_t)(s + 1) * 32 * 512;
#pragma unroll
      for (int j = 0; j < 8; ++j) {
        int i = t + j * 256, r = i >> 6, q = i & 63;
        wreg[j] = *(const float4*)(Wn + (size_t)r * 512 + q * 4);
      }
    }
    const int sc = s * 32;
#pragma unroll
    for (int kq = 0; kq < 8; ++kq) {
      float4 av[8];
#pragma unroll
      for (int bb = 0; bb < 8; ++bb)
        av[bb] = *(const float4*)(a0 + bb * 256 + sc + kq * 4);
#pragma unroll
      for (int kk = 0; kk < 4; ++kk) {
        float4 wv = *(const float4*)&Ws[(kq * 4 + kk) * 256 + mf4];
        fma4(acc[0], fsel(av[0], kk), wv);
        fma4(acc[1], fsel(av[1], kk), wv);
        fma4(acc[2], fsel(av[2], kk), wv);
        fma4(acc[3], fsel(av[3], kk), wv);
        fma4(acc[4], fsel(av[4], kk), wv);
        fma4(acc[5], fsel(av[5], kk), wv);
        fma4(acc[6], fsel(av[6], kk), wv);
        fma4(acc[7], fsel(av[7], kk), wv);
      }
    }
  }

  // part[(ks*32 + b)*512 + m0 + mf4]: wave writes 1KB contiguous per b-row
  float* op = part + ((size_t)ks * 32 + bg * 8) * 512 + m0 + mf4;
#pragma unroll
  for (int j = 0; j < 8; ++j) *(float4*)(op + (size_t)j * 512) = acc[j];
}

// ---------------------------------------------------------------------------
// gred_ln: h1 = relu(LN(sum_ks part + gb1)). grid 32, block 512.
__global__ __launch_bounds__(512) void gred_ln(const float* __restrict__ part,
                                               const float* __restrict__ gb1,
                                               const float* __restrict__ g, const float* __restrict__ bt,
                                               float* __restrict__ h1) {
  const int b = blockIdx.x, t = threadIdx.x;
  __shared__ float red[512];
  float a = gb1[t];
  const float* pp0 = part + (size_t)b * 512 + t;
#pragma unroll 8
  for (int ks = 0; ks < 128; ++ks) a += pp0[(size_t)ks * 16384];
  float mean = block_sum(a, red, 512) * (1.f / 512.f);
  float d = a - mean;
  float var = block_sum(d * d, red, 512) * (1.f / 512.f);
  h1[b * 512 + t] = fmaxf(d * rsqrtf(var + 1e-5f) * g[t] + bt[t], 0.f);
}

// ---------------------------------------------------------------------------
// gemm_tile<KC>: C_part = A(32 x K) @ W(K x M), one (64 m x KC k) tile/block.
// grid (M/64, K/KC, E), block 256. Both A and W tiles staged into LDS with
// coalesced float4 loads (all independent -> one latency round-trip).
// Thread: 2 b x 4 m. Output: part[((kq*E+e)*32+b)*M + m].
template <int KC>
__global__ __launch_bounds__(256) void gemm_tile(const float* __restrict__ A,
                                                 const float* __restrict__ W,
                                                 float* __restrict__ outp,
                                                 int M, int aRow,
                                                 size_t aStrideE, size_t wStrideE) {
  const int mt = blockIdx.x, kq = blockIdx.y, e = blockIdx.z, NE = gridDim.z;
  const int m0 = mt * 64, k0 = kq * KC;
  const int t = threadIdx.x;
  __shared__ float Ws[KC * 64];
  __shared__ float As[32 * (KC + 4)];
  const float* Wp = W + (size_t)e * wStrideE + (size_t)k0 * M + m0;
  for (int i = t; i < KC * 16; i += 256) {
    int r = i >> 4, q = i & 15;
    *(float4*)&Ws[r * 64 + q * 4] = *(const float4*)(Wp + (size_t)r * M + q * 4);
  }
  const float* Ap = A + (size_t)e * aStrideE + k0;
  for (int i = t; i < 32 * (KC / 4); i += 256) {
    int b = i / (KC / 4), q = i % (KC / 4);
    *(float4*)&As[b * (KC + 4) + q * 4] = *(const float4*)(Ap + (size_t)b * aRow + q * 4);
  }
  __syncthreads();
  const int mf = t & 15, bg = t >> 4;
  const int b0 = bg * 2;
  float4 acc0 = make_float4(0.f, 0.f, 0.f, 0.f), acc1 = acc0;
  const float* a0 = &As[b0 * (KC + 4)];
  const float* a1 = &As[(b0 + 1) * (KC + 4)];
#pragma unroll 8
  for (int k = 0; k < KC; ++k) {
    float4 wv = *(const float4*)&Ws[k * 64 + mf * 4];
    fma4(acc0, a0[k], wv);
    fma4(acc1, a1[k], wv);
  }
  float* op = outp + ((size_t)(kq * NE + e) * 32 + b0) * M + m0 + mf * 4;
  *(float4*)op = acc0;
  *(float4*)(op + M) = acc1;
}

// ---------------------------------------------------------------------------
// red_ln: out = [relu](LN(sum_kq zp + bias)). grid 32, block M.
__global__ void red_ln(const float* __restrict__ zp, const float* __restrict__ bias,
                       const float* __restrict__ g, const float* __restrict__ bt,
                       float* __restrict__ outp, int M, int nq, int relu) {
  const int b = blockIdx.x, t = threadIdx.x;
  __shared__ float red[512];
  float a = bias[t];
#pragma unroll 4
  for (int kq = 0; kq < nq; ++kq) a += zp[((size_t)kq * 32 + b) * M + t];
  float fM = 1.f / (float)M;
  float mean = block_sum(a, red, M) * fM;
  float d = a - mean;
  float var = block_sum(d * d, red, M) * fM;
  float v = d * rsqrtf(var + 1e-5f) * g[t] + bt[t];
  outp[b * M + t] = relu ? fmaxf(v, 0.f) : v;
}

// ---------------------------------------------------------------------------
// gate_k: emb = sum_kq zp2 + gb3; d2 to protos; softmax -> wgt. grid 32, block 128.
__global__ __launch_bounds__(128) void gate_k(const float* __restrict__ zp2,
                                              const float* __restrict__ gb3,
                                              const float* __restrict__ protos,
                                              const float* __restrict__ temp,
                                              float* __restrict__ wgt) {
  __shared__ float red[128];
  __shared__ float d2s[8];
  const int b = blockIdx.x, t = threadIdx.x;
  float a = gb3[t];
#pragma unroll 4
  for (int kq = 0; kq < 16; ++kq) a += zp2[((size_t)kq * 32 + b) * 128 + t];
  for (int e = 0; e < 8; ++e) {
    float dd = a - protos[e * 128 + t];
    float s = block_sum(dd * dd, red, 128);
    if (t == 0) d2s[e] = s;
  }
  __syncthreads();
  if (t == 0) {
    float tt = fminf(fmaxf(temp[0], 0.1f), 5.0f);
    float lg[8], mx = -1e30f;
#pragma unroll
    for (int e = 0; e < 8; ++e) {
      float dist = sqrtf(fmaxf(d2s[e], 1e-12f));
      lg[e] = -dist / tt;
      mx = fmaxf(mx, lg[e]);
    }
    float se = 0.f;
#pragma unroll
    for (int e = 0; e < 8; ++e) { lg[e] = expf(lg[e] - mx); se += lg[e]; }
#pragma unroll
    for (int e = 0; e < 8; ++e) wgt[b * 8 + e] = lg[e] / se;
  }
}

// ---------------------------------------------------------------------------
// he_k: he_all[e][b][h] = relu(x_last[b] . eW1[e][:,h] + eb1[e][h]).
// grid (8 e, 2 h-halves), block 256. eW1 half-tile (64x256 = 64 KB) staged in LDS.
__global__ __launch_bounds__(256) void he_k(const float* __restrict__ x,
                                            const float* __restrict__ eW1,
                                            const float* __restrict__ eb1,
                                            float* __restrict__ he_all) {
  const int e = blockIdx.x, hs = blockIdx.y;
  const int t = threadIdx.x;
  __shared__ float xs[32 * 64];
  __shared__ float Ws[64 * 256];
  for (int i = t; i < 512; i += 256) {  // xs: 512 float4
    int b = i >> 4, q = i & 15;
    *(float4*)&xs[b * 64 + q * 4] = *(const float4*)(x + (size_t)b * DIMK + 32704 + q * 4);
  }
  const float* w1 = eW1 + (size_t)e * 64 * 512 + hs * 256;
  for (int i = t; i < 64 * 64; i += 256) {  // Ws: 4096 float4, 16/thread
    int k = i >> 6, q = i & 63;
    *(float4*)&Ws[k * 256 + q * 4] = *(const float4*)(w1 + (size_t)k * 512 + q * 4);
  }
  __syncthreads();
  float acc[32];
#pragma unroll
  for (int b = 0; b < 32; ++b) acc[b] = 0.f;
#pragma unroll 4
  for (int k = 0; k < 64; ++k) {
    float wk = Ws[k * 256 + t];
#pragma unroll
    for (int b = 0; b < 32; ++b) acc[b] += xs[b * 64 + k] * wk;
  }
  float bb = eb1[e * 512 + hs * 256 + t];
  for (int b = 0; b < 32; ++b)
    he_all[((size_t)e * 32 + b) * 512 + hs * 256 + t] = fmaxf(acc[b] + bb, 0.f);
}

// ---------------------------------------------------------------------------
// ffuse: fused[b] = sum_e w[b,e]*(sum_kq epart[kq][e][b] + eb2[e]). grid 32, block 512.
__global__ __launch_bounds__(512) void ffuse(const float* __restrict__ epart,
                                             const float* __restrict__ eb2,
                                             const float* __restrict__ wgt,
                                             float* __restrict__ fused) {
  const int b = blockIdx.x, t = threadIdx.x;
  __shared__ float wl[8];
  if (t < 8) wl[t] = wgt[b * 8 + t];
  __syncthreads();
  float a = 0.f;
#pragma unroll
  for (int e = 0; e < 8; ++e) {
    float s = eb2[e * 512 + t];
#pragma unroll
    for (int kq = 0; kq < 8; ++kq)
      s += epart[(((size_t)kq * 8 + e) * 32 + b) * 512 + t];
    a += wl[e] * s;
  }
  fused[b * 512 + t] = a;
}

// ---------------------------------------------------------------------------
// fin_red: out[b][pi][o] = LN_o(sum_kq fpart + pb2). block 256 = 4 rows of 64
// lanes; grid 768 (3072 rows / 4).
__global__ __launch_bounds__(256) void fin_red(const float* __restrict__ fpart,
                                               const float* __restrict__ pb2,
                                               const float* __restrict__ ong,
                                               const float* __restrict__ onb,
                                               float* __restrict__ outp) {
  const int t = threadIdx.x;
  const int lane = t & 63, w = t >> 6;
  const int r = blockIdx.x * 4 + w;  // 0..3071
  const int b = r / 96, pi = r % 96;
  const int m = pi * 64 + lane;
  float a = pb2[m];
#pragma unroll
  for (int kq = 0; kq < 8; ++kq) a += fpart[((size_t)kq * 32 + b) * 6144 + m];
  float s = a;
  s += __shfl_xor(s, 1); s += __shfl_xor(s, 2); s += __shfl_xor(s, 4);
  s += __shfl_xor(s, 8); s += __shfl_xor(s, 16); s += __shfl_xor(s, 32);
  float mean = s * (1.f / 64.f);
  float d = a - mean;
  float q = d * d;
  q += __shfl_xor(q, 1); q += __shfl_xor(q, 2); q += __shfl_xor(q, 4);
  q += __shfl_xor(q, 8); q += __shfl_xor(q, 16); q += __shfl_xor(q, 32);
  float rr = rsqrtf(q * (1.f / 64.f) + 1e-5f);
  outp[((size_t)b * 96 + pi) * 64 + lane] = d * rr * ong[lane] + onb[lane];
}

extern "C" void kernel_launch(void* const* d_in, const int* in_sizes, int n_in,
                              void* d_out, int out_size, void* d_ws, size_t ws_size,
                              hipStream_t stream) {
  (void)in_sizes; (void)n_in; (void)out_size; (void)ws_size;
  const float* x      = (const float*)d_in[0];
  const float* gW1    = (const float*)d_in[1];
  const float* gb1    = (const float*)d_in[2];
  const float* gln1_g = (const float*)d_in[3];
  const float* gln1_b = (const float*)d_in[4];
  const float* gW2    = (const float*)d_in[5];
  const float* gb2    = (const float*)d_in[6];
  const float* gln2_g = (const float*)d_in[7];
  const float* gln2_b = (const float*)d_in[8];
  const float* gW3    = (const float*)d_in[9];
  const float* gb3    = (const float*)d_in[10];
  const float* protos = (const float*)d_in[11];
  const float* temp   = (const float*)d_in[12];
  const float* eW1    = (const float*)d_in[13];
  const float* eb1    = (const float*)d_in[14];
  const float* eW2    = (const float*)d_in[15];
  const float* eb2    = (const float*)d_in[16];
  const float* fW1    = (const float*)d_in[17];
  const float* fb1    = (const float*)d_in[18];
  const float* fln_g  = (const float*)d_in[19];
  const float* fln_b  = (const float*)d_in[20];
  const float* fW2    = (const float*)d_in[21];
  const float* fb2    = (const float*)d_in[22];
  const float* ln_g   = (const float*)d_in[23];
  const float* ln_b   = (const float*)d_in[24];
  const float* pW1    = (const float*)d_in[25];
  const float* pb1    = (const float*)d_in[26];
  const float* pln_g  = (const float*)d_in[27];
  const float* pln_b  = (const float*)d_in[28];
  const float* pW2    = (const float*)d_in[29];
  const float* pb2    = (const float*)d_in[30];
  const float* on_g   = (const float*)d_in[31];
  const float* on_b   = (const float*)d_in[32];
  float* out = (float*)d_out;

  float* ws     = (float*)d_ws;
  // region 0 (2,097,152 floats): gemm1 partials; after gred_ln reused as
  //   epart [0 .. 1,048,576) and he_all [1,048,576 .. 1,179,648);
  //   after ffuse reused as fpart [0 .. 1,572,864).
  float* part   = ws;
  float* epart  = ws;
  float* he_all = ws + 1048576;
  float* fpart  = ws;
  float* h1     = ws + 2097152;     // 16384
  float* h2     = h1 + 16384;
  float* zp     = h2 + 16384;       // 262144 (16 kq x 32 x 512)
  float* zp2    = zp + 262144;      // 65536 (16 kq x 32 x 128)
  float* wgt    = zp2 + 65536;      // 256
  float* fused  = wgt + 256;        // 16384
  float* f1     = fused + 16384;    // 16384
  float* lastv  = f1 + 16384;       // 16384
  float* pp     = lastv + 16384;    // 8192

  // g-path
  gemm1<<<dim3(2, 128), 256, 0, stream>>>(x, gW1, part);
  gred_ln<<<32, 512, 0, stream>>>(part, gb1, gln1_g, gln1_b, h1);
  gemm_tile<32><<<dim3(8, 16, 1), 256, 0, stream>>>(h1, gW2, zp, 512, 512, 0, 0);
  red_ln<<<32, 512, 0, stream>>>(zp, gb2, gln2_g, gln2_b, h2, 512, 16, 1);
  gemm_tile<32><<<dim3(2, 16, 1), 256, 0, stream>>>(h2, gW3, zp2, 128, 512, 0, 0);
  gate_k<<<32, 128, 0, stream>>>(zp2, gb3, protos, temp, wgt);

  // expert path (reuses region 0 after gred_ln)
  he_k<<<dim3(8, 2), 256, 0, stream>>>(x, eW1, eb1, he_all);
  gemm_tile<64><<<dim3(8, 8, 8), 256, 0, stream>>>(he_all, eW2, epart, 512, 512,
                                                   (size_t)32 * 512, (size_t)512 * 512);
  ffuse<<<32, 512, 0, stream>>>(epart, eb2, wgt, fused);

  // f-path
  gemm_tile<32><<<dim3(8, 16, 1), 256, 0, stream>>>(fused, fW1, zp, 512, 512, 0, 0);
  red_ln<<<32, 512, 0, stream>>>(zp, fb1, fln_g, fln_b, f1, 512, 16, 1);
  gemm_tile<32><<<dim3(8, 16, 1), 256, 0, stream>>>(f1, fW2, zp, 512, 512, 0, 0);
  red_ln<<<32, 512, 0, stream>>>(zp, fb2, ln_g, ln_b, lastv, 512, 16, 0);
  gemm_tile<32><<<dim3(4, 16, 1), 256, 0, stream>>>(lastv, pW1, zp, 256, 512, 0, 0);
  red_ln<<<32, 256, 0, stream>>>(zp, pb1, pln_g, pln_b, pp, 256, 16, 1);

  // final projection + LN(64)
  gemm_tile<32><<<dim3(96, 8, 1), 256, 0, stream>>>(pp, pW2, fpart, 6144, 256, 0, 0);
  fin_red<<<768, 256, 0, stream>>>(fpart, pb2, on_g, on_b, out);
}

// Round 2
// 276.766 us; speedup vs baseline: 1.0915x; 1.0915x over previous
//
#include <hip/hip_runtime.h>
#include <math.h>

// Shapes: B=32, S=512, I=64, H=512, E=8, P=96, O=64, EM=512; D = S*I = 32768.
#define DIMK 32768

__device__ __forceinline__ void fma4(float4& a, float s, const float4 w) {
  a.x += s * w.x; a.y += s * w.y; a.z += s * w.z; a.w += s * w.w;
}

__device__ __forceinline__ float fsel(const float4& v, int kk) {
  return kk == 0 ? v.x : kk == 1 ? v.y : kk == 2 ? v.z : v.w;
}

// Direct global->LDS DMA, 16 B per lane. LDS dest must be wave-uniform base +
// lane*16 (our staging layouts are exactly linear in lane index).
__device__ __forceinline__ void gld_lds16(const float* g, float* l) {
  __builtin_amdgcn_global_load_lds(
      (const __attribute__((address_space(1))) void*)g,
      (__attribute__((address_space(3))) void*)l, 16, 0, 0);
}

__device__ __forceinline__ float block_sum(float v, float* red, int n) {
  int t = threadIdx.x;
  red[t] = v;
  __syncthreads();
  for (int s = n >> 1; s > 0; s >>= 1) {
    if (t < s) red[t] += red[t + s];
    __syncthreads();
  }
  float r = red[0];
  __syncthreads();
  return r;
}

// ---------------------------------------------------------------------------
// gemm1: part[ks][b][m] = x(32 x 32768)[,k-slice ks] @ gW1[k-slice][m-tile].
// grid (4 mt of 128 m, 128 ks of 256 k) = 512 blocks (2/CU), block 256.
// Tile 32b x 128m x 256k; thread = 4b x 4m (mf = t&31, bg = t>>5).
// A staged once (32 KB); W double-buffered in 32k x 128m (16 KB) sub-stages,
// both via global_load_lds width=16 (no VGPR round-trip; loads issued right
// after the barrier stay in flight under the 32k compute phase and are
// drained by the next __syncthreads' vmcnt(0)). LDS 64 KB -> 2 blocks/CU.
__global__ __launch_bounds__(256) void gemm1(const float* __restrict__ x,
                                             const float* __restrict__ gW1,
                                             float* __restrict__ part) {
  const int mt = blockIdx.x, ks = blockIdx.y;
  const int m0 = mt * 128, k0 = ks * 256;
  const int t = threadIdx.x;
  __shared__ float As[32 * 256];     // [b][k], 32 KB
  __shared__ float Ws[2][32 * 128];  // [k][m] sub-stage, 16 KB each

  const float* Wp = gW1 + (size_t)k0 * 512 + m0;

  // stage A: 2048 x 16B, 8 per thread; dest is linear in i -> legal DMA layout
#pragma unroll
  for (int j = 0; j < 8; ++j) {
    int i = t + j * 256;
    gld_lds16(x + (size_t)(i >> 6) * DIMK + k0 + (i & 63) * 4, &As[i * 4]);
  }
  // W sub-stage 0
#pragma unroll
  for (int j = 0; j < 4; ++j) {
    int i = t + j * 256;
    gld_lds16(Wp + (size_t)(i >> 5) * 512 + (i & 31) * 4, &Ws[0][i * 4]);
  }

  const int mf4 = (t & 31) * 4;  // m-offset within tile
  const int bg = t >> 5;         // b-quad: b = bg*4 .. bg*4+3
  float4 acc[4];
#pragma unroll
  for (int j = 0; j < 4; ++j) acc[j] = make_float4(0.f, 0.f, 0.f, 0.f);
  const float* a0 = &As[bg * 4 * 256];

  for (int s = 0; s < 8; ++s) {
    // drains the DMA into Ws[s&1] (and As at s=0); joins all readers of
    // Ws[(s+1)&1] from the previous iteration before we overwrite it.
    __syncthreads();
    if (s < 7) {
      const float* Wn = Wp + (size_t)(s + 1) * 32 * 512;
#pragma unroll
      for (int j = 0; j < 4; ++j) {
        int i = t + j * 256;
        gld_lds16(Wn + (size_t)(i >> 5) * 512 + (i & 31) * 4, &Ws[(s + 1) & 1][i * 4]);
      }
    }
    const float* Wc = Ws[s & 1];
    const int sc = s * 32;
#pragma unroll
    for (int kq = 0; kq < 8; ++kq) {
      // A as float4 over k: 4 reads per 4k (2 distinct addrs/wave, 2-way free)
      float4 av0 = *(const float4*)(a0 + sc + kq * 4);
      float4 av1 = *(const float4*)(a0 + 256 + sc + kq * 4);
      float4 av2 = *(const float4*)(a0 + 512 + sc + kq * 4);
      float4 av3 = *(const float4*)(a0 + 768 + sc + kq * 4);
#pragma unroll
      for (int kk = 0; kk < 4; ++kk) {
        float4 wv = *(const float4*)&Wc[(kq * 4 + kk) * 128 + mf4];
        fma4(acc[0], fsel(av0, kk), wv);
        fma4(acc[1], fsel(av1, kk), wv);
        fma4(acc[2], fsel(av2, kk), wv);
        fma4(acc[3], fsel(av3, kk), wv);
      }
    }
  }

  float* op = part + ((size_t)ks * 32 + bg * 4) * 512 + m0 + mf4;
#pragma unroll
  for (int j = 0; j < 4; ++j) *(float4*)(op + (size_t)j * 512) = acc[j];
}

// ---------------------------------------------------------------------------
// part_red: pre[c][b][m] = sum of 16 ks-slices of part. grid (32 b, 8 c),
// block 512 -> 256 blocks, fully coalesced 8 MB read at chip-wide parallelism.
__global__ __launch_bounds__(512) void part_red(const float* __restrict__ part,
                                                float* __restrict__ pre) {
  const int b = blockIdx.x, c = blockIdx.y, t = threadIdx.x;
  float a = 0.f;
  const float* p = part + ((size_t)c * 16 * 32 + b) * 512 + t;
#pragma unroll
  for (int i = 0; i < 16; ++i) a += p[(size_t)i * 16384];
  pre[((size_t)c * 32 + b) * 512 + t] = a;
}

// ---------------------------------------------------------------------------
// gemm_tile<KC>: C_part = A(32 x K) @ W(K x M), one (64 m x KC k) tile/block.
// grid (M/64, K/KC, E), block 256. Both A and W tiles staged into LDS with
// coalesced float4 loads. Thread: 2 b x 4 m. Output: part[((kq*E+e)*32+b)*M+m].
template <int KC>
__global__ __launch_bounds__(256) void gemm_tile(const float* __restrict__ A,
                                                 const float* __restrict__ W,
                                                 float* __restrict__ outp,
                                                 int M, int aRow,
                                                 size_t aStrideE, size_t wStrideE) {
  const int mt = blockIdx.x, kq = blockIdx.y, e = blockIdx.z, NE = gridDim.z;
  const int m0 = mt * 64, k0 = kq * KC;
  const int t = threadIdx.x;
  __shared__ float Ws[KC * 64];
  __shared__ float As[32 * (KC + 4)];
  const float* Wp = W + (size_t)e * wStrideE + (size_t)k0 * M + m0;
  for (int i = t; i < KC * 16; i += 256) {
    int r = i >> 4, q = i & 15;
    *(float4*)&Ws[r * 64 + q * 4] = *(const float4*)(Wp + (size_t)r * M + q * 4);
  }
  const float* Ap = A + (size_t)e * aStrideE + k0;
  for (int i = t; i < 32 * (KC / 4); i += 256) {
    int b = i / (KC / 4), q = i % (KC / 4);
    *(float4*)&As[b * (KC + 4) + q * 4] = *(const float4*)(Ap + (size_t)b * aRow + q * 4);
  }
  __syncthreads();
  const int mf = t & 15, bg = t >> 4;
  const int b0 = bg * 2;
  float4 acc0 = make_float4(0.f, 0.f, 0.f, 0.f), acc1 = acc0;
  const float* a0 = &As[b0 * (KC + 4)];
  const float* a1 = &As[(b0 + 1) * (KC + 4)];
#pragma unroll 8
  for (int k = 0; k < KC; ++k) {
    float4 wv = *(const float4*)&Ws[k * 64 + mf * 4];
    fma4(acc0, a0[k], wv);
    fma4(acc1, a1[k], wv);
  }
  float* op = outp + ((size_t)(kq * NE + e) * 32 + b0) * M + m0 + mf * 4;
  *(float4*)op = acc0;
  *(float4*)(op + M) = acc1;
}

// ---------------------------------------------------------------------------
// red_ln: out = [relu](LN(sum_kq zp + bias)). grid 32, block M.
__global__ void red_ln(const float* __restrict__ zp, const float* __restrict__ bias,
                       const float* __restrict__ g, const float* __restrict__ bt,
                       float* __restrict__ outp, int M, int nq, int relu) {
  const int b = blockIdx.x, t = threadIdx.x;
  __shared__ float red[512];
  float a = bias[t];
#pragma unroll 4
  for (int kq = 0; kq < nq; ++kq) a += zp[((size_t)kq * 32 + b) * M + t];
  float fM = 1.f / (float)M;
  float mean = block_sum(a, red, M) * fM;
  float d = a - mean;
  float var = block_sum(d * d, red, M) * fM;
  float v = d * rsqrtf(var + 1e-5f) * g[t] + bt[t];
  outp[b * M + t] = relu ? fmaxf(v, 0.f) : v;
}

// ---------------------------------------------------------------------------
// gate_k: emb = sum_kq zp2 + gb3; d2 to protos; softmax -> wgt. grid 32, block 128.
__global__ __launch_bounds__(128) void gate_k(const float* __restrict__ zp2,
                                              const float* __restrict__ gb3,
                                              const float* __restrict__ protos,
                                              const float* __restrict__ temp,
                                              float* __restrict__ wgt) {
  __shared__ float red[128];
  __shared__ float d2s[8];
  const int b = blockIdx.x, t = threadIdx.x;
  float a = gb3[t];
#pragma unroll
  for (int kq = 0; kq < 8; ++kq) a += zp2[((size_t)kq * 32 + b) * 128 + t];
  for (int e = 0; e < 8; ++e) {
    float dd = a - protos[e * 128 + t];
    float s = block_sum(dd * dd, red, 128);
    if (t == 0) d2s[e] = s;
  }
  __syncthreads();
  if (t == 0) {
    float tt = fminf(fmaxf(temp[0], 0.1f), 5.0f);
    float lg[8], mx = -1e30f;
#pragma unroll
    for (int e = 0; e < 8; ++e) {
      float dist = sqrtf(fmaxf(d2s[e], 1e-12f));
      lg[e] = -dist / tt;
      mx = fmaxf(mx, lg[e]);
    }
    float se = 0.f;
#pragma unroll
    for (int e = 0; e < 8; ++e) { lg[e] = expf(lg[e] - mx); se += lg[e]; }
#pragma unroll
    for (int e = 0; e < 8; ++e) wgt[b * 8 + e] = lg[e] / se;
  }
}

// ---------------------------------------------------------------------------
// he_k: he_all[e][b][h] = relu(x_last[b] . eW1[e][:,h] + eb1[e][h]).
// grid (8 e, 2 h-halves), block 256. eW1 half-tile (64x256 = 64 KB) staged in LDS.
__global__ __launch_bounds__(256) void he_k(const float* __restrict__ x,
                                            const float* __restrict__ eW1,
                                            const float* __restrict__ eb1,
                                            float* __restrict__ he_all) {
  const int e = blockIdx.x, hs = blockIdx.y;
  const int t = threadIdx.x;
  __shared__ float xs[32 * 64];
  __shared__ float Ws[64 * 256];
  for (int i = t; i < 512; i += 256) {  // xs: 512 float4
    int b = i >> 4, q = i & 15;
    *(float4*)&xs[b * 64 + q * 4] = *(const float4*)(x + (size_t)b * DIMK + 32704 + q * 4);
  }
  const float* w1 = eW1 + (size_t)e * 64 * 512 + hs * 256;
  for (int i = t; i < 64 * 64; i += 256) {  // Ws: 4096 float4, 16/thread
    int k = i >> 6, q = i & 63;
    *(float4*)&Ws[k * 256 + q * 4] = *(const float4*)(w1 + (size_t)k * 512 + q * 4);
  }
  __syncthreads();
  float acc[32];
#pragma unroll
  for (int b = 0; b < 32; ++b) acc[b] = 0.f;
#pragma unroll 4
  for (int k = 0; k < 64; ++k) {
    float wk = Ws[k * 256 + t];
#pragma unroll
    for (int b = 0; b < 32; ++b) acc[b] += xs[b * 64 + k] * wk;
  }
  float bb = eb1[e * 512 + hs * 256 + t];
  for (int b = 0; b < 32; ++b)
    he_all[((size_t)e * 32 + b) * 512 + hs * 256 + t] = fmaxf(acc[b] + bb, 0.f);
}

// ---------------------------------------------------------------------------
// ffuse: fused[b][m] = sum_e w[b,e]*(sum_kq epart + eb2[e]). No cross-m
// coupling -> grid (32 b, 4 m-chunks), block 128 (4x the CUs of before).
__global__ __launch_bounds__(128) void ffuse(const float* __restrict__ epart,
                                             const float* __restrict__ eb2,
                                             const float* __restrict__ wgt,
                                             float* __restrict__ fused) {
  const int b = blockIdx.x, t = blockIdx.y * 128 + threadIdx.x;
  __shared__ float wl[8];
  if (threadIdx.x < 8) wl[threadIdx.x] = wgt[b * 8 + threadIdx.x];
  __syncthreads();
  float a = 0.f;
#pragma unroll
  for (int e = 0; e < 8; ++e) {
    float s = eb2[e * 512 + t];
#pragma unroll
    for (int kq = 0; kq < 8; ++kq)
      s += epart[(((size_t)kq * 8 + e) * 32 + b) * 512 + t];
    a += wl[e] * s;
  }
  fused[b * 512 + t] = a;
}

// ---------------------------------------------------------------------------
// fin_red: out[b][pi][o] = LN_o(sum_kq fpart + pb2), kq = 4. block 256 = 4 rows
// of 64 lanes; grid 768 (3072 rows / 4).
__global__ __launch_bounds__(256) void fin_red(const float* __restrict__ fpart,
                                               const float* __restrict__ pb2,
                                               const float* __restrict__ ong,
                                               const float* __restrict__ onb,
                                               float* __restrict__ outp) {
  const int t = threadIdx.x;
  const int lane = t & 63, w = t >> 6;
  const int r = blockIdx.x * 4 + w;  // 0..3071
  const int b = r / 96, pi = r % 96;
  const int m = pi * 64 + lane;
  float a = pb2[m];
#pragma unroll
  for (int kq = 0; kq < 4; ++kq) a += fpart[((size_t)kq * 32 + b) * 6144 + m];
  float s = a;
  s += __shfl_xor(s, 1); s += __shfl_xor(s, 2); s += __shfl_xor(s, 4);
  s += __shfl_xor(s, 8); s += __shfl_xor(s, 16); s += __shfl_xor(s, 32);
  float mean = s * (1.f / 64.f);
  float d = a - mean;
  float q = d * d;
  q += __shfl_xor(q, 1); q += __shfl_xor(q, 2); q += __shfl_xor(q, 4);
  q += __shfl_xor(q, 8); q += __shfl_xor(q, 16); q += __shfl_xor(q, 32);
  float rr = rsqrtf(q * (1.f / 64.f) + 1e-5f);
  outp[((size_t)b * 96 + pi) * 64 + lane] = d * rr * ong[lane] + onb[lane];
}

extern "C" void kernel_launch(void* const* d_in, const int* in_sizes, int n_in,
                              void* d_out, int out_size, void* d_ws, size_t ws_size,
                              hipStream_t stream) {
  (void)in_sizes; (void)n_in; (void)out_size; (void)ws_size;
  const float* x      = (const float*)d_in[0];
  const float* gW1    = (const float*)d_in[1];
  const float* gb1    = (const float*)d_in[2];
  const float* gln1_g = (const float*)d_in[3];
  const float* gln1_b = (const float*)d_in[4];
  const float* gW2    = (const float*)d_in[5];
  const float* gb2    = (const float*)d_in[6];
  const float* gln2_g = (const float*)d_in[7];
  const float* gln2_b = (const float*)d_in[8];
  const float* gW3    = (const float*)d_in[9];
  const float* gb3    = (const float*)d_in[10];
  const float* protos = (const float*)d_in[11];
  const float* temp   = (const float*)d_in[12];
  const float* eW1    = (const float*)d_in[13];
  const float* eb1    = (const float*)d_in[14];
  const float* eW2    = (const float*)d_in[15];
  const float* eb2    = (const float*)d_in[16];
  const float* fW1    = (const float*)d_in[17];
  const float* fb1    = (const float*)d_in[18];
  const float* fln_g  = (const float*)d_in[19];
  const float* fln_b  = (const float*)d_in[20];
  const float* fW2    = (const float*)d_in[21];
  const float* fb2    = (const float*)d_in[22];
  const float* ln_g   = (const float*)d_in[23];
  const float* ln_b   = (const float*)d_in[24];
  const float* pW1    = (const float*)d_in[25];
  const float* pb1    = (const float*)d_in[26];
  const float* pln_g  = (const float*)d_in[27];
  const float* pln_b  = (const float*)d_in[28];
  const float* pW2    = (const float*)d_in[29];
  const float* pb2    = (const float*)d_in[30];
  const float* on_g   = (const float*)d_in[31];
  const float* on_b   = (const float*)d_in[32];
  float* out = (float*)d_out;

  float* ws     = (float*)d_ws;
  // region 0 (2,097,152 floats): gemm1 partials; after part_red reused as
  //   epart [0 .. 1,048,576) and he_all [1,048,576 .. 1,179,648);
  //   after ffuse reused as fpart [0 .. 786,432).
  float* part   = ws;
  float* epart  = ws;
  float* he_all = ws + 1048576;
  float* fpart  = ws;
  float* h1     = ws + 2097152;     // 16384
  float* h2     = h1 + 16384;
  float* zp     = h2 + 16384;       // 262144 max (also doubles as `pre`: 8x32x512)
  float* zp2    = zp + 262144;      // 32768 (8 kq x 32 x 128)
  float* wgt    = zp2 + 65536;      // 256
  float* fused  = wgt + 256;        // 16384
  float* f1     = fused + 16384;    // 16384
  float* lastv  = f1 + 16384;       // 16384
  float* pp     = lastv + 16384;    // 8192

  // g-path
  gemm1<<<dim3(4, 128), 256, 0, stream>>>(x, gW1, part);
  part_red<<<dim3(32, 8), 512, 0, stream>>>(part, zp);
  red_ln<<<32, 512, 0, stream>>>(zp, gb1, gln1_g, gln1_b, h1, 512, 8, 1);
  gemm_tile<64><<<dim3(8, 8, 1), 256, 0, stream>>>(h1, gW2, zp, 512, 512, 0, 0);
  red_ln<<<32, 512, 0, stream>>>(zp, gb2, gln2_g, gln2_b, h2, 512, 8, 1);
  gemm_tile<64><<<dim3(2, 8, 1), 256, 0, stream>>>(h2, gW3, zp2, 128, 512, 0, 0);
  gate_k<<<32, 128, 0, stream>>>(zp2, gb3, protos, temp, wgt);

  // expert path (reuses region 0 after part_red)
  he_k<<<dim3(8, 2), 256, 0, stream>>>(x, eW1, eb1, he_all);
  gemm_tile<64><<<dim3(8, 8, 8), 256, 0, stream>>>(he_all, eW2, epart, 512, 512,
                                                   (size_t)32 * 512, (size_t)512 * 512);
  ffuse<<<dim3(32, 4), 128, 0, stream>>>(epart, eb2, wgt, fused);

  // f-path
  gemm_tile<64><<<dim3(8, 8, 1), 256, 0, stream>>>(fused, fW1, zp, 512, 512, 0, 0);
  red_ln<<<32, 512, 0, stream>>>(zp, fb1, fln_g, fln_b, f1, 512, 8, 1);
  gemm_tile<64><<<dim3(8, 8, 1), 256, 0, stream>>>(f1, fW2, zp, 512, 512, 0, 0);
  red_ln<<<32, 512, 0, stream>>>(zp, fb2, ln_g, ln_b, lastv, 512, 8, 0);
  gemm_tile<64><<<dim3(4, 8, 1), 256, 0, stream>>>(lastv, pW1, zp, 256, 512, 0, 0);
  red_ln<<<32, 256, 0, stream>>>(zp, pb1, pln_g, pln_b, pp, 256, 8, 1);

  // final projection + LN(64)
  gemm_tile<64><<<dim3(96, 4, 1), 256, 0, stream>>>(pp, pW2, fpart, 6144, 256, 0, 0);
  fin_red<<<768, 256, 0, stream>>>(fpart, pb2, on_g, on_b, out);
}